// Round 7
// baseline (112.413 us; speedup 1.0000x reference)
//
#include <hip/hip_runtime.h>
#include <hip/hip_bf16.h>
#include <stdint.h>

#define VOCAB 200000
#define EDIM 128
#define NTREES 2048
#define KNODES 511

typedef __attribute__((ext_vector_type(4))) float f32x4;
typedef __attribute__((ext_vector_type(2))) float f32x2;
typedef __attribute__((ext_vector_type(8))) short s16x8;
typedef __attribute__((ext_vector_type(8))) unsigned short u16x8;

__device__ __forceinline__ unsigned short f2bf(float x) {
  unsigned u = __builtin_bit_cast(unsigned, x);
  return (unsigned short)((u + 0x7fffu + ((u >> 16) & 1u)) >> 16);  // RNE
}
__device__ __forceinline__ float bf2f(unsigned short h) {
  unsigned u = ((unsigned)h) << 16;
  return __builtin_bit_cast(float, u);
}

// ---- manual OCP e4m3fn codec (fallback paths only) ----
__device__ __forceinline__ unsigned fp8enc(float v) {
  unsigned u = __builtin_bit_cast(unsigned, v);
  unsigned s = (u >> 24) & 0x80u;
  unsigned au = u & 0x7fffffffu;
  au = au > 0x43E00000u ? 0x43E00000u : au;            // clamp to 448
  unsigned r = au + 0x0007ffffu + ((au >> 20) & 1u);   // RNE to 3 mantissa bits
  unsigned code = (((r >> 23) - 120u) << 3) | ((r >> 20) & 7u);
  float a = __builtin_bit_cast(float, au);
  unsigned sub = (unsigned)(int)rintf(a * 512.0f);     // subnormal: multiples of 2^-9
  unsigned c = (au < 0x3C800000u) ? sub : code;        // 2^-6 boundary
  return c | s;
}
__device__ __forceinline__ float fp8dec(unsigned b) {
  unsigned e = (b >> 3) & 15u, m = b & 7u;
  float n = __builtin_bit_cast(float, ((e + 120u) << 23) | (m << 20));
  float sv = (float)(int)m * 0.001953125f;             // m * 2^-9
  float v = e ? n : sv;
  return (b & 0x80u) ? -v : v;
}

// pack 4 f32 -> 4 fp8 bytes (HW cvt when available; OCP e4m3fn on gfx950)
__device__ __forceinline__ unsigned enc4(float a, float b, float c, float d) {
#if __has_builtin(__builtin_amdgcn_cvt_pk_fp8_f32)
  int pk = 0;
  pk = __builtin_amdgcn_cvt_pk_fp8_f32(a, b, pk, false);
  pk = __builtin_amdgcn_cvt_pk_fp8_f32(c, d, pk, true);
  return (unsigned)pk;
#else
  return fp8enc(a) | (fp8enc(b) << 8) | (fp8enc(c) << 16) | (fp8enc(d) << 24);
#endif
}

// decode 8 fp8 bytes -> 8 f32 (HW packed cvt when available)
__device__ __forceinline__ void dec8(uint2 v, float* o) {
#if __has_builtin(__builtin_amdgcn_cvt_pk_f32_fp8)
  f32x2 a = __builtin_amdgcn_cvt_pk_f32_fp8(v.x, false);
  f32x2 b = __builtin_amdgcn_cvt_pk_f32_fp8(v.x, true);
  f32x2 c = __builtin_amdgcn_cvt_pk_f32_fp8(v.y, false);
  f32x2 d = __builtin_amdgcn_cvt_pk_f32_fp8(v.y, true);
  o[0] = a[0]; o[1] = a[1]; o[2] = b[0]; o[3] = b[1];
  o[4] = c[0]; o[5] = c[1]; o[6] = d[0]; o[7] = d[1];
#else
#pragma unroll
  for (int i = 0; i < 4; ++i) o[i] = fp8dec((v.x >> (8 * i)) & 0xFFu);
#pragma unroll
  for (int i = 0; i < 4; ++i) o[4 + i] = fp8dec((v.y >> (8 * i)) & 0xFFu);
#endif
}

// 8 f32 -> bf16x8 fragment via native casts (compiler fuses into v_cvt_pk_bf16_f32)
__device__ __forceinline__ s16x8 cvt8(f32x4 a, f32x4 b) {
  u16x8 t;
#pragma unroll
  for (int i = 0; i < 4; ++i)
    t[i] = __builtin_bit_cast(unsigned short, __float2bfloat16(a[i]));
#pragma unroll
  for (int i = 0; i < 4; ++i)
    t[4 + i] = __builtin_bit_cast(unsigned short, __float2bfloat16(b[i]));
  return __builtin_bit_cast(s16x8, t);
}

// ---------------- Kernel 0: one-shot W/bias prep (write-coalesced) ----------------
// WTb[n][k] = bf16(W[k][n] * 64); bsc[n] = b[n] * 64.
// Thread idx: n = idx>>7, k = idx&127 -> consecutive threads write consecutive k.
__global__ __launch_bounds__(256) void wprep_kernel(
    const float* __restrict__ W, const float* __restrict__ b,
    unsigned short* __restrict__ WTb, float* __restrict__ bsc) {
  int idx = blockIdx.x * 256 + threadIdx.x;
  if (idx < EDIM * EDIM) {
    int n = idx >> 7, k = idx & 127;
    WTb[idx] = f2bf(W[k * EDIM + n] * 64.0f);   // strided read (32KB, L2), coalesced write
  }
  if (idx < EDIM) bsc[idx] = b[idx] * 64.0f;
}

// ---------------- Kernel 1: T8[v][d] = fp8( 64*(emb[v,:]@W[:,d] + b[d]) ) ----------------
// v5: thin-and-deep for memory-level parallelism. 16 rows/wave, acc[8] (32 AGPR),
// ALL 8 emb f32x4 loads issued at wave entry; ~4-5 waves/SIMD occupancy.
__global__ __launch_bounds__(256, 4) void proj_kernel(
    const float* __restrict__ emb, const unsigned short* __restrict__ WTb,
    const float* __restrict__ bsc, unsigned char* __restrict__ T8) {
  const int tid = threadIdx.x;
  const int w = tid >> 6, lane = tid & 63;
  const int q = lane >> 4, cl = lane & 15;
  const long row = (long)blockIdx.x * 64 + w * 16 + cl;   // 200000 = 3125*64: no tail
  const float* rp = emb + row * EDIM + q * 8;

  // fire the wave's entire emb working set (8 independent 16B loads)
  f32x4 ea[4], eb[4];
#pragma unroll
  for (int ks = 0; ks < 4; ++ks) {
    ea[ks] = *(const f32x4*)(rp + ks * 32);
    eb[ks] = *(const f32x4*)(rp + ks * 32 + 4);
  }

  // acc init = bias fragment (col0 = nt*16 + q*4)
  f32x4 acc[8];
#pragma unroll
  for (int nt = 0; nt < 8; ++nt) acc[nt] = *(const f32x4*)(bsc + nt * 16 + q * 4);

#pragma unroll
  for (int ks = 0; ks < 4; ++ks) {
    s16x8 ef = cvt8(ea[ks], eb[ks]);
    const unsigned short* wbase = WTb + ks * 32 + q * 8;
#pragma unroll
    for (int nt = 0; nt < 8; ++nt) {
      s16x8 wf = *(const s16x8*)(wbase + (nt * 16 + cl) * EDIM);
      acc[nt] = __builtin_amdgcn_mfma_f32_16x16x32_bf16(wf, ef, acc[nt], 0, 0, 0);
    }
  }

  // D[m][n]: m = 4q+r = out-col within nt tile, n = cl = row. 8 packed-u32 stores.
#pragma unroll
  for (int nt = 0; nt < 8; ++nt) {
    const int col0 = nt * 16 + q * 4;
    *(unsigned*)&T8[row * EDIM + col0] =
        enc4(acc[nt][0], acc[nt][1], acc[nt][2], acc[nt][3]);
  }
}

// ---------------- Kernel 2: one block = one tree, full 128-dim fp8 rows ----------------
// (unchanged — ~9 us: single-line gather, overlaid bf16 sums, 2 blocks/CU)
__global__ __launch_bounds__(512, 4) void tree_kernel(
    const unsigned char* __restrict__ T8, const int* __restrict__ tokens,
    float* __restrict__ out) {
  __shared__ unsigned char P8[512][EDIM];          // 64 KiB
  unsigned char* lds = &P8[0][0];
  const int SOFF = 16384;                          // S: 128 slots x 288 B
  const int MOFF = 53248;                          // mb: 8 x 128 f32

  const int tid = threadIdx.x;
  const int tree = blockIdx.x;
  const int wv = tid >> 6, lane = tid & 63;

  // --- gather: 8 DMA instrs/wave, 8 rows x 8 lanes; source chunk-XOR swizzled ---
  const int* tk = tokens + (long)tree * KNODES;
  int toks[8];
#pragma unroll
  for (int i = 0; i < 8; ++i) {
    int node = wv * 64 + i * 8 + (lane >> 3);
    toks[i] = tk[node > 510 ? 510 : node];         // row 511 = dup, never read
  }
  const int chunk = (lane & 7) ^ ((lane >> 3) & 7);  // row&7 == lane>>3 here
#pragma unroll
  for (int i = 0; i < 8; ++i) {
    const unsigned char* src = T8 + (long)toks[i] * EDIM + chunk * 16;
    unsigned char* dst = &P8[wv * 64 + i * 8][0];  // wave-uniform; HW adds lane*16
    __builtin_amdgcn_global_load_lds(
        (const __attribute__((address_space(1))) unsigned int*)src,
        (__attribute__((address_space(3))) unsigned int*)dst, 16, 0, 0);
  }
  __syncthreads();

  // LDS chunk c of row r holds global chunk c^(r&7); to read global chunk g use g^(r&7).
  auto ldP8 = [&](int row, int q8) -> uint2 {      // 8 fp8 at dims q8*8
    int g = q8 >> 1, h = q8 & 1;
    return *(const uint2*)(lds + row * 128 + (((g ^ (row & 7))) << 4) + h * 8);
  };
  auto saddr = [&](int slot, int q16) -> unsigned char* {  // 16B chunk q16 of sum slot
    return lds + SOFF + slot * 288 + ((q16 ^ (slot & 7)) << 4);
  };

  const int q = tid & 15;          // dim chunk: dims q*8 .. q*8+7
  const int jg = tid >> 4;         // 0..31
  float rmax[8];
#pragma unroll
  for (int e = 0; e < 8; ++e) rmax[e] = 0.f;       // 0-init folds final ReLU clamp

  // --- level 7 (parents 127..254): register-staged (reads must precede overlay) ---
  u16x8 sp7[4];
#pragma unroll
  for (int k = 0; k < 4; ++k) {
    const int p = jg + 32 * k, m = 127 + p;
    uint2 pr = ldP8(m, q);
    uint2 xr = ldP8(2 * m + 1, q);
    uint2 yr = ldP8(2 * m + 2, q);
    float pv[8], xv[8], yv[8];
    dec8(pr, pv); dec8(xr, xv); dec8(yr, yv);
#pragma unroll
    for (int e = 0; e < 8; ++e) {
      float sv = pv[e] + xv[e] + yv[e];
      rmax[e] = fmaxf(rmax[e], fmaxf(fmaxf(xv[e], yv[e]), sv));  // leaves + sum
      sp7[k][e] = f2bf(sv);
    }
  }
  __syncthreads();                 // ALL level-7 reads done before overlay writes
#pragma unroll
  for (int k = 0; k < 4; ++k) *(u16x8*)saddr(jg + 32 * k, q) = sp7[k];
  __syncthreads();

  // --- levels 6..0: parent fp8 from P8 rows <127 (intact), children sums from S ---
  for (int l = 6; l >= 0; --l) {
    const int cnt = 1 << l;
    for (int p = jg; p < cnt; p += 32) {
      const int m = cnt - 1 + p;
      const int ps = p << (7 - l);
      const int c2s = ps + (1 << (6 - l));
      uint2 pr = ldP8(m, q);
      u16x8 c1 = *(const u16x8*)saddr(ps, q);
      u16x8 c2 = *(const u16x8*)saddr(c2s, q);
      float pv[8];
      dec8(pr, pv);
      u16x8 sp;
#pragma unroll
      for (int e = 0; e < 8; ++e) {
        float sv = pv[e] + bf2f(c1[e]) + bf2f(c2[e]);
        rmax[e] = fmaxf(rmax[e], sv);              // children already tracked
        sp[e] = f2bf(sv);
      }
      *(u16x8*)saddr(ps, q) = sp;                  // overwrites own c1 slot (safe)
    }
    __syncthreads();
  }

  // --- final max: shuffle over jg within wave, then LDS ---
#pragma unroll
  for (int e = 0; e < 8; ++e) {
    rmax[e] = fmaxf(rmax[e], __shfl_xor(rmax[e], 16, 64));
    rmax[e] = fmaxf(rmax[e], __shfl_xor(rmax[e], 32, 64));
  }
  float* mb = (float*)(lds + MOFF);
  if (lane < 16) {
#pragma unroll
    for (int e = 0; e < 8; ++e) mb[wv * 128 + lane * 8 + e] = rmax[e];
  }
  __syncthreads();
  if (tid < 128) {
    float v = mb[tid];
#pragma unroll
    for (int w2 = 1; w2 < 8; ++w2) v = fmaxf(v, mb[w2 * 128 + tid]);
    out[(long)tree * 128 + tid] = v * 0.015625f;   // /64 exact
  }
}

extern "C" void kernel_launch(void* const* d_in, const int* in_sizes, int n_in,
                              void* d_out, int out_size, void* d_ws, size_t ws_size,
                              hipStream_t stream) {
  const float* emb = (const float*)d_in[0];
  const float* W = (const float*)d_in[1];
  const float* b = (const float*)d_in[2];
  const int* tokens = (const int*)d_in[3];
  // d_in[4..6] (parent/level/batch_id) are structural — recomputed from index math.

  unsigned char* T8 = (unsigned char*)d_ws;                         // 25.6 MB
  unsigned short* WTb = (unsigned short*)((char*)d_ws + 25600000);  // 32 KB
  float* bsc = (float*)((char*)d_ws + 25632768);                    // 512 B
  float* out = (float*)d_out;

  wprep_kernel<<<64, 256, 0, stream>>>(W, b, WTb, bsc);
  proj_kernel<<<VOCAB / 64, 256, 0, stream>>>(emb, WTb, bsc, T8);   // 3125 blocks
  tree_kernel<<<NTREES, 512, 0, stream>>>(T8, tokens, out);
}

// Round 8
// 76.164 us; speedup vs baseline: 1.4759x; 1.4759x over previous
//
#include <hip/hip_runtime.h>
#include <hip/hip_bf16.h>
#include <stdint.h>

#define VOCAB 200000
#define EDIM 128
#define NTREES 2048
#define KNODES 511
#define PROJ_BLOCKS 512   // persistent: 2 blocks/CU

typedef __attribute__((ext_vector_type(4))) float f32x4;
typedef __attribute__((ext_vector_type(2))) float f32x2;
typedef __attribute__((ext_vector_type(8))) short s16x8;
typedef __attribute__((ext_vector_type(8))) unsigned short u16x8;

__device__ __forceinline__ unsigned short f2bf(float x) {
  unsigned u = __builtin_bit_cast(unsigned, x);
  return (unsigned short)((u + 0x7fffu + ((u >> 16) & 1u)) >> 16);  // RNE
}
__device__ __forceinline__ float bf2f(unsigned short h) {
  unsigned u = ((unsigned)h) << 16;
  return __builtin_bit_cast(float, u);
}

// ---- manual OCP e4m3fn codec (fallback paths only) ----
__device__ __forceinline__ unsigned fp8enc(float v) {
  unsigned u = __builtin_bit_cast(unsigned, v);
  unsigned s = (u >> 24) & 0x80u;
  unsigned au = u & 0x7fffffffu;
  au = au > 0x43E00000u ? 0x43E00000u : au;            // clamp to 448
  unsigned r = au + 0x0007ffffu + ((au >> 20) & 1u);   // RNE to 3 mantissa bits
  unsigned code = (((r >> 23) - 120u) << 3) | ((r >> 20) & 7u);
  float a = __builtin_bit_cast(float, au);
  unsigned sub = (unsigned)(int)rintf(a * 512.0f);     // subnormal: multiples of 2^-9
  unsigned c = (au < 0x3C800000u) ? sub : code;        // 2^-6 boundary
  return c | s;
}
__device__ __forceinline__ float fp8dec(unsigned b) {
  unsigned e = (b >> 3) & 15u, m = b & 7u;
  float n = __builtin_bit_cast(float, ((e + 120u) << 23) | (m << 20));
  float sv = (float)(int)m * 0.001953125f;             // m * 2^-9
  float v = e ? n : sv;
  return (b & 0x80u) ? -v : v;
}

// pack 4 f32 -> 4 fp8 bytes (HW cvt when available; OCP e4m3fn on gfx950)
__device__ __forceinline__ unsigned enc4(float a, float b, float c, float d) {
#if __has_builtin(__builtin_amdgcn_cvt_pk_fp8_f32)
  int pk = 0;
  pk = __builtin_amdgcn_cvt_pk_fp8_f32(a, b, pk, false);
  pk = __builtin_amdgcn_cvt_pk_fp8_f32(c, d, pk, true);
  return (unsigned)pk;
#else
  return fp8enc(a) | (fp8enc(b) << 8) | (fp8enc(c) << 16) | (fp8enc(d) << 24);
#endif
}

// decode 8 fp8 bytes -> 8 f32 (HW packed cvt when available)
__device__ __forceinline__ void dec8(uint2 v, float* o) {
#if __has_builtin(__builtin_amdgcn_cvt_pk_f32_fp8)
  f32x2 a = __builtin_amdgcn_cvt_pk_f32_fp8(v.x, false);
  f32x2 b = __builtin_amdgcn_cvt_pk_f32_fp8(v.x, true);
  f32x2 c = __builtin_amdgcn_cvt_pk_f32_fp8(v.y, false);
  f32x2 d = __builtin_amdgcn_cvt_pk_f32_fp8(v.y, true);
  o[0] = a[0]; o[1] = a[1]; o[2] = b[0]; o[3] = b[1];
  o[4] = c[0]; o[5] = c[1]; o[6] = d[0]; o[7] = d[1];
#else
#pragma unroll
  for (int i = 0; i < 4; ++i) o[i] = fp8dec((v.x >> (8 * i)) & 0xFFu);
#pragma unroll
  for (int i = 0; i < 4; ++i) o[4 + i] = fp8dec((v.y >> (8 * i)) & 0xFFu);
#endif
}

// 8 f32 -> bf16x8 fragment via native casts (compiler fuses into v_cvt_pk_bf16_f32)
__device__ __forceinline__ s16x8 cvt8(f32x4 a, f32x4 b) {
  u16x8 t;
#pragma unroll
  for (int i = 0; i < 4; ++i)
    t[i] = __builtin_bit_cast(unsigned short, __float2bfloat16(a[i]));
#pragma unroll
  for (int i = 0; i < 4; ++i)
    t[4 + i] = __builtin_bit_cast(unsigned short, __float2bfloat16(b[i]));
  return __builtin_bit_cast(s16x8, t);
}

// ---------------- Kernel 0: one-shot W/bias prep (write-coalesced) ----------------
__global__ __launch_bounds__(256) void wprep_kernel(
    const float* __restrict__ W, const float* __restrict__ b,
    unsigned short* __restrict__ WTb, float* __restrict__ bsc) {
  int idx = blockIdx.x * 256 + threadIdx.x;
  if (idx < EDIM * EDIM) {
    int n = idx >> 7, k = idx & 127;
    WTb[idx] = f2bf(W[k * EDIM + n] * 64.0f);   // strided read (32KB, L2), coalesced write
  }
  if (idx < EDIM) bsc[idx] = b[idx] * 64.0f;
}

// ---------------- Kernel 1: T8[v][d] = fp8( 64*(emb[v,:]@W[:,d] + b[d]) ) ----------------
// v6: persistent grid-stride; W (32x16B) + bias preloaded into registers ONCE.
// Inner loop has ZERO global loads besides the 8 independent emb f32x4 streams:
// no per-MFMA vmcnt drains -> wave critical path = emb latency only, overlapped
// across 8 resident waves/CU.
__global__ __launch_bounds__(256, 2) void proj_kernel(
    const float* __restrict__ emb, const unsigned short* __restrict__ WTb,
    const float* __restrict__ bsc, unsigned char* __restrict__ T8) {
  const int tid = threadIdx.x;
  const int w = tid >> 6, lane = tid & 63;
  const int q = lane >> 4, cl = lane & 15;

  // --- once per block: all W fragments + bias fragment into registers ---
  s16x8 wf[4][8];                        // [ks][nt] : 128 VGPR
#pragma unroll
  for (int ks = 0; ks < 4; ++ks)
#pragma unroll
    for (int nt = 0; nt < 8; ++nt)
      wf[ks][nt] = *(const s16x8*)(WTb + (nt * 16 + cl) * EDIM + ks * 32 + q * 8);

  f32x4 bb[8];                           // bias fragment: 32 VGPR
#pragma unroll
  for (int nt = 0; nt < 8; ++nt) bb[nt] = *(const f32x4*)(bsc + nt * 16 + q * 4);

  // --- grid-stride over 64-row tiles (200000 = 3125 * 64, no tail) ---
  const int NT = VOCAB / 64;             // 3125
  for (int t = blockIdx.x; t < NT; t += PROJ_BLOCKS) {
    const long row = (long)t * 64 + w * 16 + cl;
    const float* rp = emb + row * EDIM + q * 8;

    f32x4 ea[4], eb[4];                  // 8 independent 16B loads, all issued here
#pragma unroll
    for (int ks = 0; ks < 4; ++ks) {
      ea[ks] = *(const f32x4*)(rp + ks * 32);
      eb[ks] = *(const f32x4*)(rp + ks * 32 + 4);
    }

    f32x4 acc[8];
#pragma unroll
    for (int nt = 0; nt < 8; ++nt) acc[nt] = bb[nt];

#pragma unroll
    for (int ks = 0; ks < 4; ++ks) {
      s16x8 ef = cvt8(ea[ks], eb[ks]);
#pragma unroll
      for (int nt = 0; nt < 8; ++nt)     // pure-register MFMA burst
        acc[nt] = __builtin_amdgcn_mfma_f32_16x16x32_bf16(wf[ks][nt], ef, acc[nt], 0, 0, 0);
    }

#pragma unroll
    for (int nt = 0; nt < 8; ++nt) {
      const int col0 = nt * 16 + q * 4;
      *(unsigned*)&T8[row * EDIM + col0] =
          enc4(acc[nt][0], acc[nt][1], acc[nt][2], acc[nt][3]);
    }
  }
}

// ---------------- Kernel 2: one block = one tree, full 128-dim fp8 rows ----------------
// (unchanged — ~9 us: single-line gather, overlaid bf16 sums, 2 blocks/CU)
__global__ __launch_bounds__(512, 4) void tree_kernel(
    const unsigned char* __restrict__ T8, const int* __restrict__ tokens,
    float* __restrict__ out) {
  __shared__ unsigned char P8[512][EDIM];          // 64 KiB
  unsigned char* lds = &P8[0][0];
  const int SOFF = 16384;                          // S: 128 slots x 288 B
  const int MOFF = 53248;                          // mb: 8 x 128 f32

  const int tid = threadIdx.x;
  const int tree = blockIdx.x;
  const int wv = tid >> 6, lane = tid & 63;

  const int* tk = tokens + (long)tree * KNODES;
  int toks[8];
#pragma unroll
  for (int i = 0; i < 8; ++i) {
    int node = wv * 64 + i * 8 + (lane >> 3);
    toks[i] = tk[node > 510 ? 510 : node];         // row 511 = dup, never read
  }
  const int chunk = (lane & 7) ^ ((lane >> 3) & 7);  // row&7 == lane>>3 here
#pragma unroll
  for (int i = 0; i < 8; ++i) {
    const unsigned char* src = T8 + (long)toks[i] * EDIM + chunk * 16;
    unsigned char* dst = &P8[wv * 64 + i * 8][0];  // wave-uniform; HW adds lane*16
    __builtin_amdgcn_global_load_lds(
        (const __attribute__((address_space(1))) unsigned int*)src,
        (__attribute__((address_space(3))) unsigned int*)dst, 16, 0, 0);
  }
  __syncthreads();

  auto ldP8 = [&](int row, int q8) -> uint2 {      // 8 fp8 at dims q8*8
    int g = q8 >> 1, h = q8 & 1;
    return *(const uint2*)(lds + row * 128 + (((g ^ (row & 7))) << 4) + h * 8);
  };
  auto saddr = [&](int slot, int q16) -> unsigned char* {
    return lds + SOFF + slot * 288 + ((q16 ^ (slot & 7)) << 4);
  };

  const int q = tid & 15;
  const int jg = tid >> 4;
  float rmax[8];
#pragma unroll
  for (int e = 0; e < 8; ++e) rmax[e] = 0.f;       // 0-init folds final ReLU clamp

  u16x8 sp7[4];
#pragma unroll
  for (int k = 0; k < 4; ++k) {
    const int p = jg + 32 * k, m = 127 + p;
    uint2 pr = ldP8(m, q);
    uint2 xr = ldP8(2 * m + 1, q);
    uint2 yr = ldP8(2 * m + 2, q);
    float pv[8], xv[8], yv[8];
    dec8(pr, pv); dec8(xr, xv); dec8(yr, yv);
#pragma unroll
    for (int e = 0; e < 8; ++e) {
      float sv = pv[e] + xv[e] + yv[e];
      rmax[e] = fmaxf(rmax[e], fmaxf(fmaxf(xv[e], yv[e]), sv));  // leaves + sum
      sp7[k][e] = f2bf(sv);
    }
  }
  __syncthreads();                 // ALL level-7 reads done before overlay writes
#pragma unroll
  for (int k = 0; k < 4; ++k) *(u16x8*)saddr(jg + 32 * k, q) = sp7[k];
  __syncthreads();

  for (int l = 6; l >= 0; --l) {
    const int cnt = 1 << l;
    for (int p = jg; p < cnt; p += 32) {
      const int m = cnt - 1 + p;
      const int ps = p << (7 - l);
      const int c2s = ps + (1 << (6 - l));
      uint2 pr = ldP8(m, q);
      u16x8 c1 = *(const u16x8*)saddr(ps, q);
      u16x8 c2 = *(const u16x8*)saddr(c2s, q);
      float pv[8];
      dec8(pr, pv);
      u16x8 sp;
#pragma unroll
      for (int e = 0; e < 8; ++e) {
        float sv = pv[e] + bf2f(c1[e]) + bf2f(c2[e]);
        rmax[e] = fmaxf(rmax[e], sv);
        sp[e] = f2bf(sv);
      }
      *(u16x8*)saddr(ps, q) = sp;
    }
    __syncthreads();
  }

#pragma unroll
  for (int e = 0; e < 8; ++e) {
    rmax[e] = fmaxf(rmax[e], __shfl_xor(rmax[e], 16, 64));
    rmax[e] = fmaxf(rmax[e], __shfl_xor(rmax[e], 32, 64));
  }
  float* mb = (float*)(lds + MOFF);
  if (lane < 16) {
#pragma unroll
    for (int e = 0; e < 8; ++e) mb[wv * 128 + lane * 8 + e] = rmax[e];
  }
  __syncthreads();
  if (tid < 128) {
    float v = mb[tid];
#pragma unroll
    for (int w2 = 1; w2 < 8; ++w2) v = fmaxf(v, mb[w2 * 128 + tid]);
    out[(long)tree * 128 + tid] = v * 0.015625f;   // /64 exact
  }
}

extern "C" void kernel_launch(void* const* d_in, const int* in_sizes, int n_in,
                              void* d_out, int out_size, void* d_ws, size_t ws_size,
                              hipStream_t stream) {
  const float* emb = (const float*)d_in[0];
  const float* W = (const float*)d_in[1];
  const float* b = (const float*)d_in[2];
  const int* tokens = (const int*)d_in[3];
  // d_in[4..6] (parent/level/batch_id) are structural — recomputed from index math.

  unsigned char* T8 = (unsigned char*)d_ws;                         // 25.6 MB
  unsigned short* WTb = (unsigned short*)((char*)d_ws + 25600000);  // 32 KB
  float* bsc = (float*)((char*)d_ws + 25632768);                    // 512 B
  float* out = (float*)d_out;

  wprep_kernel<<<64, 256, 0, stream>>>(W, b, WTb, bsc);
  proj_kernel<<<PROJ_BLOCKS, 256, 0, stream>>>(emb, WTb, bsc, T8);
  tree_kernel<<<NTREES, 512, 0, stream>>>(T8, tokens, out);
}

// Round 9
// 66.377 us; speedup vs baseline: 1.6936x; 1.1474x over previous
//
#include <hip/hip_runtime.h>
#include <hip/hip_bf16.h>
#include <stdint.h>

#define VOCAB 200000
#define EDIM 128
#define NTREES 2048
#define KNODES 511

typedef __attribute__((ext_vector_type(4))) float f32x4;
typedef __attribute__((ext_vector_type(2))) float f32x2;
typedef __attribute__((ext_vector_type(8))) short s16x8;
typedef __attribute__((ext_vector_type(8))) unsigned short u16x8;

__device__ __forceinline__ unsigned short f2bf(float x) {
  unsigned u = __builtin_bit_cast(unsigned, x);
  return (unsigned short)((u + 0x7fffu + ((u >> 16) & 1u)) >> 16);  // RNE
}
__device__ __forceinline__ float bf2f(unsigned short h) {
  unsigned u = ((unsigned)h) << 16;
  return __builtin_bit_cast(float, u);
}

// ---- manual OCP e4m3fn codec (fallback paths only) ----
__device__ __forceinline__ unsigned fp8enc(float v) {
  unsigned u = __builtin_bit_cast(unsigned, v);
  unsigned s = (u >> 24) & 0x80u;
  unsigned au = u & 0x7fffffffu;
  au = au > 0x43E00000u ? 0x43E00000u : au;
  unsigned r = au + 0x0007ffffu + ((au >> 20) & 1u);
  unsigned code = (((r >> 23) - 120u) << 3) | ((r >> 20) & 7u);
  float a = __builtin_bit_cast(float, au);
  unsigned sub = (unsigned)(int)rintf(a * 512.0f);
  unsigned c = (au < 0x3C800000u) ? sub : code;
  return c | s;
}
__device__ __forceinline__ float fp8dec(unsigned b) {
  unsigned e = (b >> 3) & 15u, m = b & 7u;
  float n = __builtin_bit_cast(float, ((e + 120u) << 23) | (m << 20));
  float sv = (float)(int)m * 0.001953125f;
  float v = e ? n : sv;
  return (b & 0x80u) ? -v : v;
}

__device__ __forceinline__ unsigned enc4(float a, float b, float c, float d) {
#if __has_builtin(__builtin_amdgcn_cvt_pk_fp8_f32)
  int pk = 0;
  pk = __builtin_amdgcn_cvt_pk_fp8_f32(a, b, pk, false);
  pk = __builtin_amdgcn_cvt_pk_fp8_f32(c, d, pk, true);
  return (unsigned)pk;
#else
  return fp8enc(a) | (fp8enc(b) << 8) | (fp8enc(c) << 16) | (fp8enc(d) << 24);
#endif
}

__device__ __forceinline__ void dec8(uint2 v, float* o) {
#if __has_builtin(__builtin_amdgcn_cvt_pk_f32_fp8)
  f32x2 a = __builtin_amdgcn_cvt_pk_f32_fp8(v.x, false);
  f32x2 b = __builtin_amdgcn_cvt_pk_f32_fp8(v.x, true);
  f32x2 c = __builtin_amdgcn_cvt_pk_f32_fp8(v.y, false);
  f32x2 d = __builtin_amdgcn_cvt_pk_f32_fp8(v.y, true);
  o[0] = a[0]; o[1] = a[1]; o[2] = b[0]; o[3] = b[1];
  o[4] = c[0]; o[5] = c[1]; o[6] = d[0]; o[7] = d[1];
#else
#pragma unroll
  for (int i = 0; i < 4; ++i) o[i] = fp8dec((v.x >> (8 * i)) & 0xFFu);
#pragma unroll
  for (int i = 0; i < 4; ++i) o[4 + i] = fp8dec((v.y >> (8 * i)) & 0xFFu);
#endif
}

__device__ __forceinline__ s16x8 cvt8(f32x4 a, f32x4 b) {
  u16x8 t;
#pragma unroll
  for (int i = 0; i < 4; ++i)
    t[i] = __builtin_bit_cast(unsigned short, __float2bfloat16(a[i]));
#pragma unroll
  for (int i = 0; i < 4; ++i)
    t[4 + i] = __builtin_bit_cast(unsigned short, __float2bfloat16(b[i]));
  return __builtin_bit_cast(s16x8, t);
}

// ---------------- Kernel 0: one-shot W/bias prep, fragment-major ----------------
// WTb2 chunk c = fr*64 + lane (fr = ks*8+nt, lane = q*16+cl):
//   8 bf16 = W[ks*32+q*8+j][nt*16+cl] * 64, j=0..7.
// proj's per-lane W load is then 16B fully coalesced (1KB per wave-instr).
__global__ __launch_bounds__(256) void wprep_kernel(
    const float* __restrict__ W, const float* __restrict__ b,
    unsigned short* __restrict__ WTb2, float* __restrict__ bsc) {
  int c = blockIdx.x * 256 + threadIdx.x;   // 0..2047
  if (c < 2048) {
    int lane = c & 63, fr = c >> 6;
    int ks = fr >> 3, nt = fr & 7, q = lane >> 4, cl = lane & 15;
    u16x8 t;
#pragma unroll
    for (int j = 0; j < 8; ++j)
      t[j] = f2bf(W[(ks * 32 + q * 8 + j) * EDIM + nt * 16 + cl] * 64.0f);
    *(u16x8*)(WTb2 + c * 8) = t;
  }
  if (c < EDIM) bsc[c] = b[c] * 64.0f;
}

// ---------------- Kernel 1: T8[v][d] = fp8( 64*(emb[v,:]@W[:,d] + b[d]) ) ----------------
// v7: emb streamed via global_load_lds DMA (wave-private 16-row buffer, source
// chunk-XOR swizzled); W + bias pinned in registers via opaque asm (compiler
// cannot re-sink the loads). vmcnt queue = DMA + stores only; zero barriers.
__global__ __launch_bounds__(512, 2) void proj_kernel(
    const float* __restrict__ emb, const unsigned short* __restrict__ WTb2,
    const float* __restrict__ bsc, unsigned char* __restrict__ T8) {
  __shared__ float ES[8][16][EDIM];   // 64 KiB: [wave][row][k], 16B-chunk swizzled

  const int tid = threadIdx.x;
  const int wv = tid >> 6, lane = tid & 63;
  const int q = lane >> 4, cl = lane & 15;

  // --- once per wave: 32 W fragments + 8 bias fragments -> registers, pinned ---
  s16x8 wf[32];
#pragma unroll
  for (int fr = 0; fr < 32; ++fr)
    wf[fr] = *(const s16x8*)(WTb2 + (fr * 64 + lane) * 8);
  f32x4 bb[8];
#pragma unroll
  for (int nt = 0; nt < 8; ++nt)
    bb[nt] = *(const f32x4*)(bsc + nt * 16 + q * 4);
#pragma unroll
  for (int fr = 0; fr < 32; ++fr) asm volatile("" : "+v"(wf[fr]));
#pragma unroll
  for (int nt = 0; nt < 8; ++nt) asm volatile("" : "+v"(bb[nt]));

  const int gw = blockIdx.x * 8 + wv;       // 0..2047 wave-stream id
  const int NWT = VOCAB / 16;               // 12500 wave-tiles (exact)
  const int STRIDE = 256 * 8;               // 2048 wave-streams

  // DMA one 16-row tile into this wave's buffer. Source is chunk-XOR swizzled
  // within each row (key = row&7) so compute-side f32x4 reads sit at the b128
  // bank floor. Dest is linear (HW: base + lane*16).
  auto issue_dma = [&](int t) {
#pragma unroll
    for (int i = 0; i < 8; ++i) {
      int rloc = 2 * i + (lane >> 5);                       // local row 0..15
      int c5 = lane & 31;                                   // 16B chunk in row
      int csrc = (c5 & 24) | ((c5 & 7) ^ (rloc & 7));
      const float* src = emb + ((long)t * 16 + rloc) * EDIM + csrc * 4;
      __builtin_amdgcn_global_load_lds(
          (const __attribute__((address_space(1))) unsigned int*)src,
          (__attribute__((address_space(3))) unsigned int*)(&ES[wv][2 * i][0]),
          16, 0, 0);
    }
  };

  int t = gw;
  issue_dma(t);
  for (; t < NWT; t += STRIDE) {
    const int tn = t + STRIDE;

    asm volatile("s_waitcnt vmcnt(0)" ::: "memory");   // this tile's DMA landed
    __builtin_amdgcn_sched_barrier(0);

    // read my row's 8 swizzled f32x4 fragments (row = cl, key = cl&7)
    f32x4 ea[4], eb[4];
#pragma unroll
    for (int ks = 0; ks < 4; ++ks) {
      int g0 = ks * 8 + q * 2;
      int s0 = (g0 & 24) | ((g0 & 7) ^ (cl & 7));
      int g1 = g0 + 1;
      int s1 = (g1 & 24) | ((g1 & 7) ^ (cl & 7));
      const float* rb = &ES[wv][cl][0];
      ea[ks] = *(const f32x4*)(rb + s0 * 4);
      eb[ks] = *(const f32x4*)(rb + s1 * 4);
    }
    asm volatile("s_waitcnt lgkmcnt(0)" ::: "memory");  // reads done -> buffer free
    __builtin_amdgcn_sched_barrier(0);
    if (tn < NWT) issue_dma(tn);                        // prefetch next tile

    f32x4 acc[8];
#pragma unroll
    for (int nt = 0; nt < 8; ++nt) acc[nt] = bb[nt];
#pragma unroll
    for (int ks = 0; ks < 4; ++ks) {
      s16x8 ef = cvt8(ea[ks], eb[ks]);
#pragma unroll
      for (int nt = 0; nt < 8; ++nt)
        acc[nt] = __builtin_amdgcn_mfma_f32_16x16x32_bf16(wf[ks * 8 + nt], ef, acc[nt], 0, 0, 0);
    }

    const long row = (long)t * 16 + cl;
#pragma unroll
    for (int nt = 0; nt < 8; ++nt) {
      const int col0 = nt * 16 + q * 4;
      *(unsigned*)&T8[row * EDIM + col0] =
          enc4(acc[nt][0], acc[nt][1], acc[nt][2], acc[nt][3]);
    }
  }
}

// ---------------- Kernel 2: one block = one tree, full 128-dim fp8 rows ----------------
// (unchanged — ~9 us)
__global__ __launch_bounds__(512, 4) void tree_kernel(
    const unsigned char* __restrict__ T8, const int* __restrict__ tokens,
    float* __restrict__ out) {
  __shared__ unsigned char P8[512][EDIM];          // 64 KiB
  unsigned char* lds = &P8[0][0];
  const int SOFF = 16384;
  const int MOFF = 53248;

  const int tid = threadIdx.x;
  const int tree = blockIdx.x;
  const int wv = tid >> 6, lane = tid & 63;

  const int* tk = tokens + (long)tree * KNODES;
  int toks[8];
#pragma unroll
  for (int i = 0; i < 8; ++i) {
    int node = wv * 64 + i * 8 + (lane >> 3);
    toks[i] = tk[node > 510 ? 510 : node];
  }
  const int chunk = (lane & 7) ^ ((lane >> 3) & 7);
#pragma unroll
  for (int i = 0; i < 8; ++i) {
    const unsigned char* src = T8 + (long)toks[i] * EDIM + chunk * 16;
    unsigned char* dst = &P8[wv * 64 + i * 8][0];
    __builtin_amdgcn_global_load_lds(
        (const __attribute__((address_space(1))) unsigned int*)src,
        (__attribute__((address_space(3))) unsigned int*)dst, 16, 0, 0);
  }
  __syncthreads();

  auto ldP8 = [&](int row, int q8) -> uint2 {
    int g = q8 >> 1, h = q8 & 1;
    return *(const uint2*)(lds + row * 128 + (((g ^ (row & 7))) << 4) + h * 8);
  };
  auto saddr = [&](int slot, int q16) -> unsigned char* {
    return lds + SOFF + slot * 288 + ((q16 ^ (slot & 7)) << 4);
  };

  const int q = tid & 15;
  const int jg = tid >> 4;
  float rmax[8];
#pragma unroll
  for (int e = 0; e < 8; ++e) rmax[e] = 0.f;

  u16x8 sp7[4];
#pragma unroll
  for (int k = 0; k < 4; ++k) {
    const int p = jg + 32 * k, m = 127 + p;
    uint2 pr = ldP8(m, q);
    uint2 xr = ldP8(2 * m + 1, q);
    uint2 yr = ldP8(2 * m + 2, q);
    float pv[8], xv[8], yv[8];
    dec8(pr, pv); dec8(xr, xv); dec8(yr, yv);
#pragma unroll
    for (int e = 0; e < 8; ++e) {
      float sv = pv[e] + xv[e] + yv[e];
      rmax[e] = fmaxf(rmax[e], fmaxf(fmaxf(xv[e], yv[e]), sv));
      sp7[k][e] = f2bf(sv);
    }
  }
  __syncthreads();
#pragma unroll
  for (int k = 0; k < 4; ++k) *(u16x8*)saddr(jg + 32 * k, q) = sp7[k];
  __syncthreads();

  for (int l = 6; l >= 0; --l) {
    const int cnt = 1 << l;
    for (int p = jg; p < cnt; p += 32) {
      const int m = cnt - 1 + p;
      const int ps = p << (7 - l);
      const int c2s = ps + (1 << (6 - l));
      uint2 pr = ldP8(m, q);
      u16x8 c1 = *(const u16x8*)saddr(ps, q);
      u16x8 c2 = *(const u16x8*)saddr(c2s, q);
      float pv[8];
      dec8(pr, pv);
      u16x8 sp;
#pragma unroll
      for (int e = 0; e < 8; ++e) {
        float sv = pv[e] + bf2f(c1[e]) + bf2f(c2[e]);
        rmax[e] = fmaxf(rmax[e], sv);
        sp[e] = f2bf(sv);
      }
      *(u16x8*)saddr(ps, q) = sp;
    }
    __syncthreads();
  }

#pragma unroll
  for (int e = 0; e < 8; ++e) {
    rmax[e] = fmaxf(rmax[e], __shfl_xor(rmax[e], 16, 64));
    rmax[e] = fmaxf(rmax[e], __shfl_xor(rmax[e], 32, 64));
  }
  float* mb = (float*)(lds + MOFF);
  if (lane < 16) {
#pragma unroll
    for (int e = 0; e < 8; ++e) mb[wv * 128 + lane * 8 + e] = rmax[e];
  }
  __syncthreads();
  if (tid < 128) {
    float v = mb[tid];
#pragma unroll
    for (int w2 = 1; w2 < 8; ++w2) v = fmaxf(v, mb[w2 * 128 + tid]);
    out[(long)tree * 128 + tid] = v * 0.015625f;
  }
}

extern "C" void kernel_launch(void* const* d_in, const int* in_sizes, int n_in,
                              void* d_out, int out_size, void* d_ws, size_t ws_size,
                              hipStream_t stream) {
  const float* emb = (const float*)d_in[0];
  const float* W = (const float*)d_in[1];
  const float* b = (const float*)d_in[2];
  const int* tokens = (const int*)d_in[3];

  unsigned char* T8 = (unsigned char*)d_ws;                          // 25.6 MB
  unsigned short* WTb2 = (unsigned short*)((char*)d_ws + 25600000);  // 32 KB
  float* bsc = (float*)((char*)d_ws + 25632768);                     // 512 B
  float* out = (float*)d_out;

  wprep_kernel<<<8, 256, 0, stream>>>(W, b, WTb2, bsc);
  proj_kernel<<<256, 512, 0, stream>>>(emb, WTb2, bsc, T8);
  tree_kernel<<<NTREES, 512, 0, stream>>>(T8, tokens, out);
}